// Round 1
// baseline (12131.670 us; speedup 1.0000x reference)
//
#include <hip/hip_runtime.h>

#define NN 100000
#define NE 1600000
#define NG 64

// ---------------- degree / norm ----------------
__global__ __launch_bounds__(256) void k_deg(const int* __restrict__ src,
                                             const float* __restrict__ w,
                                             float* __restrict__ deg, int E) {
    int e = blockIdx.x * blockDim.x + threadIdx.x;
    if (e < E) atomicAdd(&deg[src[e]], w[e]);
}

__global__ __launch_bounds__(256) void k_dinv(float* __restrict__ deg, int N) {
    int i = blockIdx.x * blockDim.x + threadIdx.x;
    if (i < N) {
        float d = deg[i];
        deg[i] = (d > 0.f) ? rsqrtf(fmaxf(d, 1e-30f)) : 0.f;
    }
}

__global__ __launch_bounds__(256) void k_norm(const int* __restrict__ src,
                                              const int* __restrict__ dst,
                                              const float* __restrict__ w,
                                              const float* __restrict__ dinv,
                                              float* __restrict__ norm, int E) {
    int e = blockIdx.x * blockDim.x + threadIdx.x;
    if (e < E) norm[e] = -dinv[src[e]] * w[e] * dinv[dst[e]];
}

// ---------------- propagation: out[dst] += norm * in[src]  (atomic scatter) ----
template <int F>
__global__ __launch_bounds__(256) void k_prop(const int* __restrict__ src,
                                              const int* __restrict__ dst,
                                              const float* __restrict__ norm,
                                              const float* __restrict__ in,
                                              float* __restrict__ out, int E) {
    const int CPE = F / 4;  // float4 chunks per edge
    int tid = blockIdx.x * blockDim.x + threadIdx.x;
    int e = tid / CPE;
    int c = tid % CPE;
    if (e >= E) return;
    int s = src[e], d = dst[e];
    float nw = norm[e];
    float4 v = reinterpret_cast<const float4*>(in + (long long)s * F)[c];
    float* o = out + (long long)d * F + c * 4;
    atomicAdd(o + 0, v.x * nw);
    atomicAdd(o + 1, v.y * nw);
    atomicAdd(o + 2, v.z * nw);
    atomicAdd(o + 3, v.w * nw);
}

// ---------------- T2 = 2*P - T0 (elementwise, float4) ----------------
__global__ __launch_bounds__(256) void k_combine(float* __restrict__ T2,
                                                 const float* __restrict__ T0,
                                                 int n4) {
    int i = blockIdx.x * blockDim.x + threadIdx.x;
    if (i < n4) {
        float4 p = reinterpret_cast<float4*>(T2)[i];
        float4 t = reinterpret_cast<const float4*>(T0)[i];
        p.x = 2.f * p.x - t.x;
        p.y = 2.f * p.y - t.y;
        p.z = 2.f * p.z - t.z;
        p.w = 2.f * p.w - t.w;
        reinterpret_cast<float4*>(T2)[i] = p;
    }
}

// ---------------- out = relu( T0@W[0] + T1@W[1] + T2@W[2] + b ) --------------
// BM=64, BN=64 per block, 256 threads, 4x4 micro-tile per thread.
__global__ __launch_bounds__(256) void k_gemm3(const float* __restrict__ T0,
                                               const float* __restrict__ T1,
                                               const float* __restrict__ T2,
                                               const float* __restrict__ W,
                                               const float* __restrict__ bias,
                                               float* __restrict__ out,
                                               int N, int Fin, int Fout) {
    __shared__ float As[16][65];
    __shared__ float Bs[16][64];
    int row0 = blockIdx.x * 64;
    int col0 = blockIdx.y * 64;
    int tid = threadIdx.x;
    int tr = tid >> 4, tc = tid & 15;
    float acc[4][4] = {};
    const float* Ts[3] = {T0, T1, T2};
    for (int k = 0; k < 3; ++k) {
        const float* T = Ts[k];
        const float* Wk = W + k * Fin * Fout;
        for (int k0 = 0; k0 < Fin; k0 += 16) {
            // A tile: 64 rows x 16 cols
            {
                int r = row0 + (tid >> 2);
                int cc = (tid & 3) * 4;
                float4 v = make_float4(0.f, 0.f, 0.f, 0.f);
                if (r < N)
                    v = *reinterpret_cast<const float4*>(T + (long long)r * Fin + k0 + cc);
                As[cc + 0][tid >> 2] = v.x;
                As[cc + 1][tid >> 2] = v.y;
                As[cc + 2][tid >> 2] = v.z;
                As[cc + 3][tid >> 2] = v.w;
            }
            // B tile: 16 rows x 64 cols of W[k]
            {
                int rr = tid >> 4;
                int cc = (tid & 15) * 4;
                float4 v = *reinterpret_cast<const float4*>(Wk + (long long)(k0 + rr) * Fout + col0 + cc);
                *reinterpret_cast<float4*>(&Bs[rr][cc]) = v;
            }
            __syncthreads();
#pragma unroll
            for (int kk = 0; kk < 16; ++kk) {
                float a0 = As[kk][tr * 4 + 0];
                float a1 = As[kk][tr * 4 + 1];
                float a2 = As[kk][tr * 4 + 2];
                float a3 = As[kk][tr * 4 + 3];
                float4 b = *reinterpret_cast<const float4*>(&Bs[kk][tc * 4]);
                acc[0][0] += a0 * b.x; acc[0][1] += a0 * b.y; acc[0][2] += a0 * b.z; acc[0][3] += a0 * b.w;
                acc[1][0] += a1 * b.x; acc[1][1] += a1 * b.y; acc[1][2] += a1 * b.z; acc[1][3] += a1 * b.w;
                acc[2][0] += a2 * b.x; acc[2][1] += a2 * b.y; acc[2][2] += a2 * b.z; acc[2][3] += a2 * b.w;
                acc[3][0] += a3 * b.x; acc[3][1] += a3 * b.y; acc[3][2] += a3 * b.z; acc[3][3] += a3 * b.w;
            }
            __syncthreads();
        }
    }
#pragma unroll
    for (int i = 0; i < 4; ++i) {
        int r = row0 + tr * 4 + i;
        if (r >= N) continue;
#pragma unroll
        for (int j = 0; j < 4; ++j) {
            int cgl = col0 + tc * 4 + j;
            float v = acc[i][j] + bias[cgl];
            v = fmaxf(v, 0.f);
            out[(long long)r * Fout + cgl] = v;
        }
    }
}

// ---------------- pooling ----------------
__global__ __launch_bounds__(256) void k_pool(const float* __restrict__ h,
                                              const int* __restrict__ batch,
                                              float* __restrict__ sums,
                                              float* __restrict__ counts) {
    int tid = blockIdx.x * blockDim.x + threadIdx.x;
    int n = tid >> 5;
    int c = tid & 31;
    if (n >= NN) return;
    int b = batch[n];
    float4 v = reinterpret_cast<const float4*>(h + (long long)n * 128)[c];
    float* s = sums + b * 128 + c * 4;
    atomicAdd(s + 0, v.x);
    atomicAdd(s + 1, v.y);
    atomicAdd(s + 2, v.z);
    atomicAdd(s + 3, v.w);
    if (c == 0) atomicAdd(&counts[b], 1.0f);
}

__global__ __launch_bounds__(640) void k_head(const float* __restrict__ sums,
                                              const float* __restrict__ counts,
                                              const float* __restrict__ linW,
                                              const float* __restrict__ linb,
                                              float* __restrict__ out) {
    int tid = threadIdx.x;
    if (tid >= NG * 10) return;
    int g = tid / 10, o = tid % 10;
    float inv = 1.f / fmaxf(counts[g], 1.f);
    float acc = 0.f;
#pragma unroll 8
    for (int k = 0; k < 128; ++k) acc += sums[g * 128 + k] * linW[k * 10 + o];
    out[tid] = acc * inv + linb[o];
}

// ---------------- launch ----------------
extern "C" void kernel_launch(void* const* d_in, const int* in_sizes, int n_in,
                              void* d_out, int out_size, void* d_ws, size_t ws_size,
                              hipStream_t stream) {
    const float* x = (const float*)d_in[0];
    const int* ei = (const int*)d_in[1];
    const float* ew = (const float*)d_in[2];
    const int* batch = (const int*)d_in[3];
    const float* W1 = (const float*)d_in[4];
    const float* b1 = (const float*)d_in[5];
    const float* W2 = (const float*)d_in[6];
    const float* b2 = (const float*)d_in[7];
    const float* W3 = (const float*)d_in[8];
    const float* b3 = (const float*)d_in[9];
    const float* linW = (const float*)d_in[10];
    const float* linb = (const float*)d_in[11];

    const int E = in_sizes[1] / 2;   // 1,600,000
    const int N = in_sizes[0] / 128; // 100,000
    const int* src = ei;
    const int* dst = ei + E;

    float* ws = (float*)d_ws;
    float* norm = ws;                       // E
    float* deg = norm + 1600000;            // N (padded to 100096)
    float* A = deg + 100096;                // N*128   (T1)
    float* B = A + 12800000;                // N*128   (prop accum / T2)
    float* C = B + 12800000;                // N*128   (H1 then H3)
    float* D = C + 12800000;                // N*64    (H2)
    float* sums = D + 6400000;              // 64*128
    float* counts = sums + NG * 128;        // 64

    const int TB = 256;
    auto blocks = [](long long t, int b) { return (int)((t + b - 1) / b); };

    // norm
    hipMemsetAsync(deg, 0, N * sizeof(float), stream);
    k_deg<<<blocks(E, TB), TB, 0, stream>>>(src, ew, deg, E);
    k_dinv<<<blocks(N, TB), TB, 0, stream>>>(deg, N);
    k_norm<<<blocks(E, TB), TB, 0, stream>>>(src, dst, ew, deg, norm, E);

    // ---- layer 1: x (128) -> C (64) ----
    hipMemsetAsync(A, 0, (size_t)N * 128 * 4, stream);
    k_prop<128><<<blocks((long long)E * 32, TB), TB, 0, stream>>>(src, dst, norm, x, A, E);
    hipMemsetAsync(B, 0, (size_t)N * 128 * 4, stream);
    k_prop<128><<<blocks((long long)E * 32, TB), TB, 0, stream>>>(src, dst, norm, A, B, E);
    k_combine<<<blocks(N * 32, TB), TB, 0, stream>>>(B, x, N * 32);
    {
        dim3 g((N + 63) / 64, 1);
        k_gemm3<<<g, TB, 0, stream>>>(x, A, B, W1, b1, C, N, 128, 64);
    }

    // ---- layer 2: C (64) -> D (64) ----
    hipMemsetAsync(A, 0, (size_t)N * 64 * 4, stream);
    k_prop<64><<<blocks((long long)E * 16, TB), TB, 0, stream>>>(src, dst, norm, C, A, E);
    hipMemsetAsync(B, 0, (size_t)N * 64 * 4, stream);
    k_prop<64><<<blocks((long long)E * 16, TB), TB, 0, stream>>>(src, dst, norm, A, B, E);
    k_combine<<<blocks(N * 16, TB), TB, 0, stream>>>(B, C, N * 16);
    {
        dim3 g((N + 63) / 64, 1);
        k_gemm3<<<g, TB, 0, stream>>>(C, A, B, W2, b2, D, N, 64, 64);
    }

    // ---- layer 3: D (64) -> C (128) ----
    hipMemsetAsync(A, 0, (size_t)N * 64 * 4, stream);
    k_prop<64><<<blocks((long long)E * 16, TB), TB, 0, stream>>>(src, dst, norm, D, A, E);
    hipMemsetAsync(B, 0, (size_t)N * 64 * 4, stream);
    k_prop<64><<<blocks((long long)E * 16, TB), TB, 0, stream>>>(src, dst, norm, A, B, E);
    k_combine<<<blocks(N * 16, TB), TB, 0, stream>>>(B, D, N * 16);
    {
        dim3 g((N + 63) / 64, 2);
        k_gemm3<<<g, TB, 0, stream>>>(D, A, B, W3, b3, C, N, 64, 128);
    }

    // ---- pool + head ----
    hipMemsetAsync(sums, 0, (NG * 128 + NG) * sizeof(float), stream);
    k_pool<<<blocks((long long)N * 32, TB), TB, 0, stream>>>(C, batch, sums, counts);
    k_head<<<1, 640, 0, stream>>>(sums, counts, linW, linb, (float*)d_out);
}

// Round 2
// 1171.070 us; speedup vs baseline: 10.3595x; 10.3595x over previous
//
#include <hip/hip_runtime.h>

#define NN 100000
#define NG 64

// ================= degree / inverse-sqrt =================
__global__ __launch_bounds__(256) void k_deg(const int* __restrict__ src,
                                             const float* __restrict__ w,
                                             float* __restrict__ deg, int E) {
    int e = blockIdx.x * blockDim.x + threadIdx.x;
    if (e < E) atomicAdd(&deg[src[e]], w[e]);
}

__global__ __launch_bounds__(256) void k_dinv(float* __restrict__ deg, int N) {
    int i = blockIdx.x * blockDim.x + threadIdx.x;
    if (i < N) {
        float d = deg[i];
        deg[i] = (d > 0.f) ? rsqrtf(fmaxf(d, 1e-30f)) : 0.f;
    }
}

// ================= CSR build =================
__global__ __launch_bounds__(256) void k_hist(const int* __restrict__ dst,
                                              int* __restrict__ cnt, int E) {
    int e = blockIdx.x * blockDim.x + threadIdx.x;
    if (e < E) atomicAdd(&cnt[dst[e]], 1);
}

// single-block exclusive scan over N counts (in place): cnt[i] -> row start
__global__ __launch_bounds__(1024) void k_scan(int* __restrict__ cnt, int N) {
    __shared__ int sh[1024];
    int t = threadIdx.x;
    int chunk = (N + 1023) / 1024;
    int s = t * chunk;
    int e = min(s + chunk, N);
    int tot = 0;
    for (int i = s; i < e; ++i) tot += cnt[i];
    sh[t] = tot;
    __syncthreads();
    for (int off = 1; off < 1024; off <<= 1) {
        int v = (t >= off) ? sh[t - off] : 0;
        __syncthreads();
        sh[t] += v;
        __syncthreads();
    }
    int base = (t == 0) ? 0 : sh[t - 1];
    for (int i = s; i < e; ++i) {
        int c = cnt[i];
        cnt[i] = base;
        base += c;
    }
}

// fill: cursor[i] starts at row start; after fill cursor[i] == row end
__global__ __launch_bounds__(256) void k_fill(const int* __restrict__ src,
                                              const int* __restrict__ dst,
                                              const float* __restrict__ ew,
                                              const float* __restrict__ dinv,
                                              int* __restrict__ cursor,
                                              int* __restrict__ csr_src,
                                              float* __restrict__ csr_w, int E) {
    int e = blockIdx.x * blockDim.x + threadIdx.x;
    if (e >= E) return;
    int s = src[e], d = dst[e];
    int pos = atomicAdd(&cursor[d], 1);
    csr_src[pos] = s;
    csr_w[pos] = -dinv[s] * ew[e] * dinv[d];
}

// ================= propagation (CSR gather), F = 64 =================
// MODE 0: out = acc
// MODE 1: out = 2*acc - t0            (t0 stride 64)
// MODE 2: out = relu(u0 + p1 + 2*acc - u2 + bias)   (u0,u2 stride 192; p1 stride 64)
template <int MODE>
__global__ __launch_bounds__(256) void k_prop_csr(const int* __restrict__ rowend,
                                                  const int* __restrict__ csr_src,
                                                  const float* __restrict__ csr_w,
                                                  const float* __restrict__ in,
                                                  int in_stride,
                                                  float* __restrict__ out,
                                                  const float* __restrict__ t0,
                                                  const float* __restrict__ u0,
                                                  const float* __restrict__ u2,
                                                  const float* __restrict__ p1,
                                                  const float* __restrict__ bias,
                                                  int N) {
    int tid = blockIdx.x * 256 + threadIdx.x;
    int node = tid >> 4;
    int lane = tid & 15;
    if (node >= N) return;
    int start = (node == 0) ? 0 : rowend[node - 1];
    int end = rowend[node];
    float4 acc = make_float4(0.f, 0.f, 0.f, 0.f);
    int c4 = lane * 4;
    int j = start;
    for (; j + 1 < end; j += 2) {
        int s0 = csr_src[j], s1 = csr_src[j + 1];
        float w0 = csr_w[j], w1 = csr_w[j + 1];
        float4 v0 = *reinterpret_cast<const float4*>(in + s0 * in_stride + c4);
        float4 v1 = *reinterpret_cast<const float4*>(in + s1 * in_stride + c4);
        acc.x += w0 * v0.x + w1 * v1.x;
        acc.y += w0 * v0.y + w1 * v1.y;
        acc.z += w0 * v0.z + w1 * v1.z;
        acc.w += w0 * v0.w + w1 * v1.w;
    }
    if (j < end) {
        int s0 = csr_src[j];
        float w0 = csr_w[j];
        float4 v0 = *reinterpret_cast<const float4*>(in + s0 * in_stride + c4);
        acc.x += w0 * v0.x;
        acc.y += w0 * v0.y;
        acc.z += w0 * v0.z;
        acc.w += w0 * v0.w;
    }
    float4 r;
    if (MODE == 0) {
        r = acc;
    } else if (MODE == 1) {
        float4 t = *reinterpret_cast<const float4*>(t0 + node * 64 + c4);
        r.x = 2.f * acc.x - t.x;
        r.y = 2.f * acc.y - t.y;
        r.z = 2.f * acc.z - t.z;
        r.w = 2.f * acc.w - t.w;
    } else {
        float4 a = *reinterpret_cast<const float4*>(u0 + node * 192 + c4);
        float4 b = *reinterpret_cast<const float4*>(u2 + node * 192 + c4);
        float4 p = *reinterpret_cast<const float4*>(p1 + node * 64 + c4);
        float4 bb = *reinterpret_cast<const float4*>(bias + c4);
        r.x = fmaxf(a.x + p.x + 2.f * acc.x - b.x + bb.x, 0.f);
        r.y = fmaxf(a.y + p.y + 2.f * acc.y - b.y + bb.y, 0.f);
        r.z = fmaxf(a.z + p.z + 2.f * acc.z - b.z + bb.z, 0.f);
        r.w = fmaxf(a.w + p.w + 2.f * acc.w - b.w + bb.w, 0.f);
    }
    *reinterpret_cast<float4*>(out + node * 64 + c4) = r;
}

// ================= layer-1 GEMM: U = x @ W[blockIdx.y], out stride 192 ======
__global__ __launch_bounds__(256) void k_gemmU(const float* __restrict__ x,
                                               const float* __restrict__ W,
                                               float* __restrict__ U, int N) {
    __shared__ float As[16][65];
    __shared__ float Bs[16][64];
    const float* Wk = W + blockIdx.y * (128 * 64);
    int row0 = blockIdx.x * 64;
    int tid = threadIdx.x;
    int tr = tid >> 4, tc = tid & 15;
    float acc[4][4] = {};
    for (int k0 = 0; k0 < 128; k0 += 16) {
        {
            int r = row0 + (tid >> 2);
            int cc = (tid & 3) * 4;
            float4 v = make_float4(0.f, 0.f, 0.f, 0.f);
            if (r < N) v = *reinterpret_cast<const float4*>(x + (long long)r * 128 + k0 + cc);
            As[cc + 0][tid >> 2] = v.x;
            As[cc + 1][tid >> 2] = v.y;
            As[cc + 2][tid >> 2] = v.z;
            As[cc + 3][tid >> 2] = v.w;
        }
        {
            int rr = tid >> 4;
            int cc = (tid & 15) * 4;
            float4 v = *reinterpret_cast<const float4*>(Wk + (k0 + rr) * 64 + cc);
            *reinterpret_cast<float4*>(&Bs[rr][cc]) = v;
        }
        __syncthreads();
#pragma unroll
        for (int kk = 0; kk < 16; ++kk) {
            float a0 = As[kk][tr * 4 + 0];
            float a1 = As[kk][tr * 4 + 1];
            float a2 = As[kk][tr * 4 + 2];
            float a3 = As[kk][tr * 4 + 3];
            float4 b = *reinterpret_cast<const float4*>(&Bs[kk][tc * 4]);
            acc[0][0] += a0 * b.x; acc[0][1] += a0 * b.y; acc[0][2] += a0 * b.z; acc[0][3] += a0 * b.w;
            acc[1][0] += a1 * b.x; acc[1][1] += a1 * b.y; acc[1][2] += a1 * b.z; acc[1][3] += a1 * b.w;
            acc[2][0] += a2 * b.x; acc[2][1] += a2 * b.y; acc[2][2] += a2 * b.z; acc[2][3] += a2 * b.w;
            acc[3][0] += a3 * b.x; acc[3][1] += a3 * b.y; acc[3][2] += a3 * b.z; acc[3][3] += a3 * b.w;
        }
        __syncthreads();
    }
    int cbase = blockIdx.y * 64;
#pragma unroll
    for (int i = 0; i < 4; ++i) {
        int r = row0 + tr * 4 + i;
        if (r >= N) continue;
#pragma unroll
        for (int j = 0; j < 4; ++j) {
            U[(long long)r * 192 + cbase + tc * 4 + j] = acc[i][j];
        }
    }
}

// ====== 3-term GEMM: out = relu(T0@W0 + T1@W1 + T2@W2 + b); optional pool ===
template <bool POOL>
__global__ __launch_bounds__(256) void k_gemm3(const float* __restrict__ T0,
                                               const float* __restrict__ T1,
                                               const float* __restrict__ T2,
                                               const float* __restrict__ W,
                                               const float* __restrict__ bias,
                                               float* __restrict__ out,
                                               int N, int Fin, int Fout,
                                               const int* __restrict__ batch,
                                               float* __restrict__ sums) {
    __shared__ float As[16][65];
    __shared__ float Bs[16][64];
    int row0 = blockIdx.x * 64;
    int col0 = blockIdx.y * 64;
    int tid = threadIdx.x;
    int tr = tid >> 4, tc = tid & 15;
    float acc[4][4] = {};
    const float* Ts[3] = {T0, T1, T2};
    for (int k = 0; k < 3; ++k) {
        const float* T = Ts[k];
        const float* Wk = W + k * Fin * Fout;
        for (int k0 = 0; k0 < Fin; k0 += 16) {
            {
                int r = row0 + (tid >> 2);
                int cc = (tid & 3) * 4;
                float4 v = make_float4(0.f, 0.f, 0.f, 0.f);
                if (r < N)
                    v = *reinterpret_cast<const float4*>(T + (long long)r * Fin + k0 + cc);
                As[cc + 0][tid >> 2] = v.x;
                As[cc + 1][tid >> 2] = v.y;
                As[cc + 2][tid >> 2] = v.z;
                As[cc + 3][tid >> 2] = v.w;
            }
            {
                int rr = tid >> 4;
                int cc = (tid & 15) * 4;
                float4 v = *reinterpret_cast<const float4*>(Wk + (long long)(k0 + rr) * Fout + col0 + cc);
                *reinterpret_cast<float4*>(&Bs[rr][cc]) = v;
            }
            __syncthreads();
#pragma unroll
            for (int kk = 0; kk < 16; ++kk) {
                float a0 = As[kk][tr * 4 + 0];
                float a1 = As[kk][tr * 4 + 1];
                float a2 = As[kk][tr * 4 + 2];
                float a3 = As[kk][tr * 4 + 3];
                float4 b = *reinterpret_cast<const float4*>(&Bs[kk][tc * 4]);
                acc[0][0] += a0 * b.x; acc[0][1] += a0 * b.y; acc[0][2] += a0 * b.z; acc[0][3] += a0 * b.w;
                acc[1][0] += a1 * b.x; acc[1][1] += a1 * b.y; acc[1][2] += a1 * b.z; acc[1][3] += a1 * b.w;
                acc[2][0] += a2 * b.x; acc[2][1] += a2 * b.y; acc[2][2] += a2 * b.z; acc[2][3] += a2 * b.w;
                acc[3][0] += a3 * b.x; acc[3][1] += a3 * b.y; acc[3][2] += a3 * b.z; acc[3][3] += a3 * b.w;
            }
            __syncthreads();
        }
    }
    if (!POOL) {
#pragma unroll
        for (int i = 0; i < 4; ++i) {
            int r = row0 + tr * 4 + i;
            if (r >= N) continue;
#pragma unroll
            for (int j = 0; j < 4; ++j) {
                int cgl = col0 + tc * 4 + j;
                float v = fmaxf(acc[i][j] + bias[cgl], 0.f);
                out[(long long)r * Fout + cgl] = v;
            }
        }
    } else {
        __shared__ float ps[64];
        int b0 = batch[row0];
        int b1v = batch[min(row0 + 63, N - 1)];
        if (b0 == b1v) {
            if (tid < 64) ps[tid] = 0.f;
            __syncthreads();
#pragma unroll
            for (int j = 0; j < 4; ++j) {
                float cs = 0.f;
#pragma unroll
                for (int i = 0; i < 4; ++i) {
                    int r = row0 + tr * 4 + i;
                    if (r < N) cs += fmaxf(acc[i][j] + bias[col0 + tc * 4 + j], 0.f);
                }
                atomicAdd(&ps[tc * 4 + j], cs);
            }
            __syncthreads();
            if (tid < 64) atomicAdd(&sums[b0 * 128 + col0 + tid], ps[tid]);
        } else {
#pragma unroll
            for (int i = 0; i < 4; ++i) {
                int r = row0 + tr * 4 + i;
                if (r >= N) continue;
#pragma unroll
                for (int j = 0; j < 4; ++j) {
                    int cgl = col0 + tc * 4 + j;
                    float v = fmaxf(acc[i][j] + bias[cgl], 0.f);
                    atomicAdd(&sums[batch[r] * 128 + cgl], v);
                }
            }
        }
    }
}

// ================= graph starts (batch is sorted) + head =================
__global__ __launch_bounds__(128) void k_starts(const int* __restrict__ batch,
                                                int* __restrict__ starts, int N) {
    int t = threadIdx.x;
    if (t > 64) return;
    if (t == 64) { starts[64] = N; return; }
    int lo = 0, hi = N;
    while (lo < hi) {
        int mid = (lo + hi) >> 1;
        if (batch[mid] < t) lo = mid + 1; else hi = mid;
    }
    starts[t] = lo;
}

__global__ __launch_bounds__(640) void k_head(const float* __restrict__ sums,
                                              const int* __restrict__ starts,
                                              const float* __restrict__ linW,
                                              const float* __restrict__ linb,
                                              float* __restrict__ out) {
    int tid = threadIdx.x;
    if (tid >= NG * 10) return;
    int g = tid / 10, o = tid % 10;
    float cnt = (float)(starts[g + 1] - starts[g]);
    float inv = 1.f / fmaxf(cnt, 1.f);
    float acc = 0.f;
#pragma unroll 8
    for (int k = 0; k < 128; ++k) acc += sums[g * 128 + k] * linW[k * 10 + o];
    out[tid] = acc * inv + linb[o];
}

// ================= launch =================
extern "C" void kernel_launch(void* const* d_in, const int* in_sizes, int n_in,
                              void* d_out, int out_size, void* d_ws, size_t ws_size,
                              hipStream_t stream) {
    const float* x = (const float*)d_in[0];
    const int* ei = (const int*)d_in[1];
    const float* ew = (const float*)d_in[2];
    const int* batch = (const int*)d_in[3];
    const float* W1 = (const float*)d_in[4];
    const float* b1 = (const float*)d_in[5];
    const float* W2 = (const float*)d_in[6];
    const float* b2 = (const float*)d_in[7];
    const float* W3 = (const float*)d_in[8];
    const float* b3 = (const float*)d_in[9];
    const float* linW = (const float*)d_in[10];
    const float* linb = (const float*)d_in[11];

    const int E = in_sizes[1] / 2;   // 1,600,000
    const int N = in_sizes[0] / 128; // 100,000
    const int* src = ei;
    const int* dst = ei + E;

    float* ws = (float*)d_ws;
    float* csr_w  = ws;                                // 1,600,256
    int*   csr_src = (int*)(ws + 1600256);             // 1,600,256
    int*   cursor  = csr_src + 1600256;                // 100,352
    float* dinv    = (float*)(cursor + 100352);        // 100,352
    float* U       = dinv + 100352;                    // 19,200,256 (N x 192)
    float* P1      = U + 19200256;                     // 6,400,256
    float* P2      = P1 + 6400256;                     // 6,400,256
    float* H1      = P2 + 6400256;                     // 6,400,256
    float* sums    = H1 + 6400256;                     // 8,192
    int*   starts  = (int*)(sums + 8192);              // 96

    float* A2 = U;                 // layer-2 temporaries alias U (free by then)
    float* B2 = U + 6400256;
    float* H2 = U + 12800512;
    float* A3 = P1;                // layer-3 temporaries alias P1/P2
    float* B3 = P2;

    const int TB = 256;
    auto blocks = [](long long t, int b) { return (int)((t + b - 1) / b); };
    const int PG = blocks((long long)N * 16, TB);  // prop grid

    // ---- norm prep + CSR build ----
    hipMemsetAsync(dinv, 0, N * sizeof(float), stream);
    k_deg<<<blocks(E, TB), TB, 0, stream>>>(src, ew, dinv, E);
    k_dinv<<<blocks(N, TB), TB, 0, stream>>>(dinv, N);
    hipMemsetAsync(cursor, 0, N * sizeof(int), stream);
    k_hist<<<blocks(E, TB), TB, 0, stream>>>(dst, cursor, E);
    k_scan<<<1, 1024, 0, stream>>>(cursor, N);
    k_fill<<<blocks(E, TB), TB, 0, stream>>>(src, dst, ew, dinv, cursor, csr_src, csr_w, E);

    // ---- layer 1: U = x@[W0|W1|W2]; H1 = relu(U0 + prop(U1) + 2 prop(prop(U2)) - U2 + b1)
    {
        dim3 g((N + 63) / 64, 3);
        k_gemmU<<<g, TB, 0, stream>>>(x, W1, U, N);
    }
    k_prop_csr<0><<<PG, TB, 0, stream>>>(cursor, csr_src, csr_w, U + 64, 192, P1,
                                         nullptr, nullptr, nullptr, nullptr, nullptr, N);
    k_prop_csr<0><<<PG, TB, 0, stream>>>(cursor, csr_src, csr_w, U + 128, 192, P2,
                                         nullptr, nullptr, nullptr, nullptr, nullptr, N);
    k_prop_csr<2><<<PG, TB, 0, stream>>>(cursor, csr_src, csr_w, P2, 64, H1,
                                         nullptr, U, U + 128, P1, b1, N);

    // ---- layer 2: standard Cheb with gather props ----
    k_prop_csr<0><<<PG, TB, 0, stream>>>(cursor, csr_src, csr_w, H1, 64, A2,
                                         nullptr, nullptr, nullptr, nullptr, nullptr, N);
    k_prop_csr<1><<<PG, TB, 0, stream>>>(cursor, csr_src, csr_w, A2, 64, B2,
                                         H1, nullptr, nullptr, nullptr, nullptr, N);
    {
        dim3 g((N + 63) / 64, 1);
        k_gemm3<false><<<g, TB, 0, stream>>>(H1, A2, B2, W2, b2, H2, N, 64, 64, nullptr, nullptr);
    }

    // ---- layer 3: props + GEMM fused with mean-pool sums ----
    k_prop_csr<0><<<PG, TB, 0, stream>>>(cursor, csr_src, csr_w, H2, 64, A3,
                                         nullptr, nullptr, nullptr, nullptr, nullptr, N);
    k_prop_csr<1><<<PG, TB, 0, stream>>>(cursor, csr_src, csr_w, A3, 64, B3,
                                         H2, nullptr, nullptr, nullptr, nullptr, N);
    hipMemsetAsync(sums, 0, NG * 128 * sizeof(float), stream);
    {
        dim3 g((N + 63) / 64, 2);
        k_gemm3<true><<<g, TB, 0, stream>>>(H2, A3, B3, W3, b3, nullptr, N, 64, 128, batch, sums);
    }

    // ---- head ----
    k_starts<<<1, 128, 0, stream>>>(batch, starts, N);
    k_head<<<1, 640, 0, stream>>>(sums, starts, linW, linb, (float*)d_out);
}

// Round 3
// 1018.313 us; speedup vs baseline: 11.9135x; 1.1500x over previous
//
#include <hip/hip_runtime.h>

#define NN 100000
#define NG 64

// ================= fused degree + dst histogram =================
__global__ __launch_bounds__(256) void k_degh(const int* __restrict__ src,
                                              const int* __restrict__ dst,
                                              const float* __restrict__ w,
                                              float* __restrict__ deg,
                                              int* __restrict__ cnt, int E) {
    int e = blockIdx.x * blockDim.x + threadIdx.x;
    if (e < E) {
        atomicAdd(&deg[src[e]], w[e]);
        atomicAdd(&cnt[dst[e]], 1);
    }
}

__global__ __launch_bounds__(256) void k_dinv(float* __restrict__ deg, int N) {
    int i = blockIdx.x * blockDim.x + threadIdx.x;
    if (i < N) {
        float d = deg[i];
        deg[i] = (d > 0.f) ? rsqrtf(fmaxf(d, 1e-30f)) : 0.f;
    }
}

// ================= parallel exclusive scan (3 passes) =================
// pass A: per-block (1024 elems) inclusive scan in LDS; write exclusive
//         in place + block total
__global__ __launch_bounds__(1024) void k_scan_a(int* __restrict__ cnt,
                                                 int* __restrict__ bsum, int N) {
    __shared__ int sh[1024];
    int t = threadIdx.x;
    int idx = blockIdx.x * 1024 + t;
    int v = (idx < N) ? cnt[idx] : 0;
    sh[t] = v;
    __syncthreads();
#pragma unroll
    for (int off = 1; off < 1024; off <<= 1) {
        int tmp = (t >= off) ? sh[t - off] : 0;
        __syncthreads();
        sh[t] += tmp;
        __syncthreads();
    }
    if (idx < N) cnt[idx] = sh[t] - v;  // exclusive
    if (t == 1023) bsum[blockIdx.x] = sh[1023];
}

// pass B: single block scans the (<=128) block totals -> exclusive offsets
__global__ __launch_bounds__(128) void k_scan_b(const int* __restrict__ bsum,
                                                int* __restrict__ boff, int nb) {
    __shared__ int sh[128];
    int t = threadIdx.x;
    int v = (t < nb) ? bsum[t] : 0;
    sh[t] = v;
    __syncthreads();
#pragma unroll
    for (int off = 1; off < 128; off <<= 1) {
        int tmp = (t >= off) ? sh[t - off] : 0;
        __syncthreads();
        sh[t] += tmp;
        __syncthreads();
    }
    if (t < nb) boff[t] = sh[t] - v;
}

// pass C: add block offsets
__global__ __launch_bounds__(1024) void k_scan_c(int* __restrict__ cnt,
                                                 const int* __restrict__ boff, int N) {
    int idx = blockIdx.x * 1024 + threadIdx.x;
    if (idx < N) cnt[idx] += boff[blockIdx.x];
}

// ================= CSR fill =================
__global__ __launch_bounds__(256) void k_fill(const int* __restrict__ src,
                                              const int* __restrict__ dst,
                                              const float* __restrict__ ew,
                                              const float* __restrict__ dinv,
                                              int* __restrict__ cursor,
                                              int* __restrict__ csr_src,
                                              float* __restrict__ csr_w, int E) {
    int e = blockIdx.x * blockDim.x + threadIdx.x;
    if (e >= E) return;
    int s = src[e], d = dst[e];
    int pos = atomicAdd(&cursor[d], 1);
    csr_src[pos] = s;
    csr_w[pos] = -dinv[s] * ew[e] * dinv[d];
}

// ================= propagation (CSR gather) =================
// F = feature width gathered (64 or 128), CPE = F/4 lanes per node.
// MODE 0: out = acc
// MODE 1: out = 2*acc - t0                  (t0 stride 64)
// MODE 2: out = relu(u0 + p1 + 2*acc - u2 + bias)
//         (u0,u2 stride 192; p1 stride 128; out stride 64; F must be 64)
template <int F, int MODE>
__global__ __launch_bounds__(256) void k_prop_csr(const int* __restrict__ rowend,
                                                  const int* __restrict__ csr_src,
                                                  const float* __restrict__ csr_w,
                                                  const float* __restrict__ in,
                                                  int istride,
                                                  float* __restrict__ out,
                                                  int ostride,
                                                  const float* __restrict__ t0,
                                                  const float* __restrict__ u0,
                                                  const float* __restrict__ u2,
                                                  const float* __restrict__ p1,
                                                  const float* __restrict__ bias,
                                                  int N) {
    const int CPE = F / 4;
    int tid = blockIdx.x * 256 + threadIdx.x;
    int node = tid / CPE;
    int lane = tid % CPE;
    if (node >= N) return;
    int start = (node == 0) ? 0 : rowend[node - 1];
    int end = rowend[node];
    float4 acc = make_float4(0.f, 0.f, 0.f, 0.f);
    int c4 = lane * 4;
    int j = start;
    for (; j + 4 <= end; j += 4) {
        int s0 = csr_src[j + 0], s1 = csr_src[j + 1];
        int s2 = csr_src[j + 2], s3 = csr_src[j + 3];
        float w0 = csr_w[j + 0], w1 = csr_w[j + 1];
        float w2 = csr_w[j + 2], w3 = csr_w[j + 3];
        float4 v0 = *reinterpret_cast<const float4*>(in + (long long)s0 * istride + c4);
        float4 v1 = *reinterpret_cast<const float4*>(in + (long long)s1 * istride + c4);
        float4 v2 = *reinterpret_cast<const float4*>(in + (long long)s2 * istride + c4);
        float4 v3 = *reinterpret_cast<const float4*>(in + (long long)s3 * istride + c4);
        acc.x += w0 * v0.x + w1 * v1.x + w2 * v2.x + w3 * v3.x;
        acc.y += w0 * v0.y + w1 * v1.y + w2 * v2.y + w3 * v3.y;
        acc.z += w0 * v0.z + w1 * v1.z + w2 * v2.z + w3 * v3.z;
        acc.w += w0 * v0.w + w1 * v1.w + w2 * v2.w + w3 * v3.w;
    }
    for (; j < end; ++j) {
        int s0 = csr_src[j];
        float w0 = csr_w[j];
        float4 v0 = *reinterpret_cast<const float4*>(in + (long long)s0 * istride + c4);
        acc.x += w0 * v0.x;
        acc.y += w0 * v0.y;
        acc.z += w0 * v0.z;
        acc.w += w0 * v0.w;
    }
    float4 r;
    if (MODE == 0) {
        r = acc;
    } else if (MODE == 1) {
        float4 t = *reinterpret_cast<const float4*>(t0 + (long long)node * 64 + c4);
        r.x = 2.f * acc.x - t.x;
        r.y = 2.f * acc.y - t.y;
        r.z = 2.f * acc.z - t.z;
        r.w = 2.f * acc.w - t.w;
    } else {
        float4 a = *reinterpret_cast<const float4*>(u0 + (long long)node * 192 + c4);
        float4 b = *reinterpret_cast<const float4*>(u2 + (long long)node * 192 + c4);
        float4 p = *reinterpret_cast<const float4*>(p1 + (long long)node * 128 + c4);
        float4 bb = *reinterpret_cast<const float4*>(bias + c4);
        r.x = fmaxf(a.x + p.x + 2.f * acc.x - b.x + bb.x, 0.f);
        r.y = fmaxf(a.y + p.y + 2.f * acc.y - b.y + bb.y, 0.f);
        r.z = fmaxf(a.z + p.z + 2.f * acc.z - b.z + bb.z, 0.f);
        r.w = fmaxf(a.w + p.w + 2.f * acc.w - b.w + bb.w, 0.f);
    }
    *reinterpret_cast<float4*>(out + (long long)node * ostride + c4) = r;
}

// ================= layer-1 GEMM: U = x @ W[blockIdx.y], out stride 192 ======
__global__ __launch_bounds__(256) void k_gemmU(const float* __restrict__ x,
                                               const float* __restrict__ W,
                                               float* __restrict__ U, int N) {
    __shared__ float As[16][65];
    __shared__ float Bs[16][64];
    const float* Wk = W + blockIdx.y * (128 * 64);
    int row0 = blockIdx.x * 64;
    int tid = threadIdx.x;
    int tr = tid >> 4, tc = tid & 15;
    float acc[4][4] = {};
    for (int k0 = 0; k0 < 128; k0 += 16) {
        {
            int r = row0 + (tid >> 2);
            int cc = (tid & 3) * 4;
            float4 v = make_float4(0.f, 0.f, 0.f, 0.f);
            if (r < N) v = *reinterpret_cast<const float4*>(x + (long long)r * 128 + k0 + cc);
            As[cc + 0][tid >> 2] = v.x;
            As[cc + 1][tid >> 2] = v.y;
            As[cc + 2][tid >> 2] = v.z;
            As[cc + 3][tid >> 2] = v.w;
        }
        {
            int rr = tid >> 4;
            int cc = (tid & 15) * 4;
            float4 v = *reinterpret_cast<const float4*>(Wk + (k0 + rr) * 64 + cc);
            *reinterpret_cast<float4*>(&Bs[rr][cc]) = v;
        }
        __syncthreads();
#pragma unroll
        for (int kk = 0; kk < 16; ++kk) {
            float a0 = As[kk][tr * 4 + 0];
            float a1 = As[kk][tr * 4 + 1];
            float a2 = As[kk][tr * 4 + 2];
            float a3 = As[kk][tr * 4 + 3];
            float4 b = *reinterpret_cast<const float4*>(&Bs[kk][tc * 4]);
            acc[0][0] += a0 * b.x; acc[0][1] += a0 * b.y; acc[0][2] += a0 * b.z; acc[0][3] += a0 * b.w;
            acc[1][0] += a1 * b.x; acc[1][1] += a1 * b.y; acc[1][2] += a1 * b.z; acc[1][3] += a1 * b.w;
            acc[2][0] += a2 * b.x; acc[2][1] += a2 * b.y; acc[2][2] += a2 * b.z; acc[2][3] += a2 * b.w;
            acc[3][0] += a3 * b.x; acc[3][1] += a3 * b.y; acc[3][2] += a3 * b.z; acc[3][3] += a3 * b.w;
        }
        __syncthreads();
    }
    int cbase = blockIdx.y * 64;
#pragma unroll
    for (int i = 0; i < 4; ++i) {
        int r = row0 + tr * 4 + i;
        if (r >= N) continue;
#pragma unroll
        for (int j = 0; j < 4; ++j) {
            U[(long long)r * 192 + cbase + tc * 4 + j] = acc[i][j];
        }
    }
}

// ====== 3-term GEMM: out = relu(T0@W0 + T1@W1 + T2@W2 + b); optional pool ===
template <bool POOL>
__global__ __launch_bounds__(256) void k_gemm3(const float* __restrict__ T0,
                                               const float* __restrict__ T1,
                                               const float* __restrict__ T2,
                                               const float* __restrict__ W,
                                               const float* __restrict__ bias,
                                               float* __restrict__ out,
                                               int N, int Fin, int Fout,
                                               const int* __restrict__ batch,
                                               float* __restrict__ sums) {
    __shared__ float As[16][65];
    __shared__ float Bs[16][64];
    int row0 = blockIdx.x * 64;
    int col0 = blockIdx.y * 64;
    int tid = threadIdx.x;
    int tr = tid >> 4, tc = tid & 15;
    float acc[4][4] = {};
    const float* Ts[3] = {T0, T1, T2};
    for (int k = 0; k < 3; ++k) {
        const float* T = Ts[k];
        const float* Wk = W + k * Fin * Fout;
        for (int k0 = 0; k0 < Fin; k0 += 16) {
            {
                int r = row0 + (tid >> 2);
                int cc = (tid & 3) * 4;
                float4 v = make_float4(0.f, 0.f, 0.f, 0.f);
                if (r < N)
                    v = *reinterpret_cast<const float4*>(T + (long long)r * Fin + k0 + cc);
                As[cc + 0][tid >> 2] = v.x;
                As[cc + 1][tid >> 2] = v.y;
                As[cc + 2][tid >> 2] = v.z;
                As[cc + 3][tid >> 2] = v.w;
            }
            {
                int rr = tid >> 4;
                int cc = (tid & 15) * 4;
                float4 v = *reinterpret_cast<const float4*>(Wk + (long long)(k0 + rr) * Fout + col0 + cc);
                *reinterpret_cast<float4*>(&Bs[rr][cc]) = v;
            }
            __syncthreads();
#pragma unroll
            for (int kk = 0; kk < 16; ++kk) {
                float a0 = As[kk][tr * 4 + 0];
                float a1 = As[kk][tr * 4 + 1];
                float a2 = As[kk][tr * 4 + 2];
                float a3 = As[kk][tr * 4 + 3];
                float4 b = *reinterpret_cast<const float4*>(&Bs[kk][tc * 4]);
                acc[0][0] += a0 * b.x; acc[0][1] += a0 * b.y; acc[0][2] += a0 * b.z; acc[0][3] += a0 * b.w;
                acc[1][0] += a1 * b.x; acc[1][1] += a1 * b.y; acc[1][2] += a1 * b.z; acc[1][3] += a1 * b.w;
                acc[2][0] += a2 * b.x; acc[2][1] += a2 * b.y; acc[2][2] += a2 * b.z; acc[2][3] += a2 * b.w;
                acc[3][0] += a3 * b.x; acc[3][1] += a3 * b.y; acc[3][2] += a3 * b.z; acc[3][3] += a3 * b.w;
            }
            __syncthreads();
        }
    }
    if (!POOL) {
#pragma unroll
        for (int i = 0; i < 4; ++i) {
            int r = row0 + tr * 4 + i;
            if (r >= N) continue;
#pragma unroll
            for (int j = 0; j < 4; ++j) {
                int cgl = col0 + tc * 4 + j;
                float v = fmaxf(acc[i][j] + bias[cgl], 0.f);
                out[(long long)r * Fout + cgl] = v;
            }
        }
    } else {
        __shared__ float ps[64];
        int b0 = batch[row0];
        int b1v = batch[min(row0 + 63, N - 1)];
        if (b0 == b1v) {
            if (tid < 64) ps[tid] = 0.f;
            __syncthreads();
#pragma unroll
            for (int j = 0; j < 4; ++j) {
                float cs = 0.f;
#pragma unroll
                for (int i = 0; i < 4; ++i) {
                    int r = row0 + tr * 4 + i;
                    if (r < N) cs += fmaxf(acc[i][j] + bias[col0 + tc * 4 + j], 0.f);
                }
                atomicAdd(&ps[tc * 4 + j], cs);
            }
            __syncthreads();
            if (tid < 64) atomicAdd(&sums[b0 * 128 + col0 + tid], ps[tid]);
        } else {
#pragma unroll
            for (int i = 0; i < 4; ++i) {
                int r = row0 + tr * 4 + i;
                if (r >= N) continue;
#pragma unroll
                for (int j = 0; j < 4; ++j) {
                    int cgl = col0 + tc * 4 + j;
                    float v = fmaxf(acc[i][j] + bias[cgl], 0.f);
                    atomicAdd(&sums[batch[r] * 128 + cgl], v);
                }
            }
        }
    }
}

// ================= graph starts (batch is sorted) + head =================
__global__ __launch_bounds__(128) void k_starts(const int* __restrict__ batch,
                                                int* __restrict__ starts, int N) {
    int t = threadIdx.x;
    if (t > 64) return;
    if (t == 64) { starts[64] = N; return; }
    int lo = 0, hi = N;
    while (lo < hi) {
        int mid = (lo + hi) >> 1;
        if (batch[mid] < t) lo = mid + 1; else hi = mid;
    }
    starts[t] = lo;
}

__global__ __launch_bounds__(640) void k_head(const float* __restrict__ sums,
                                              const int* __restrict__ starts,
                                              const float* __restrict__ linW,
                                              const float* __restrict__ linb,
                                              float* __restrict__ out) {
    int tid = threadIdx.x;
    if (tid >= NG * 10) return;
    int g = tid / 10, o = tid % 10;
    float cnt = (float)(starts[g + 1] - starts[g]);
    float inv = 1.f / fmaxf(cnt, 1.f);
    float acc = 0.f;
#pragma unroll 8
    for (int k = 0; k < 128; ++k) acc += sums[g * 128 + k] * linW[k * 10 + o];
    out[tid] = acc * inv + linb[o];
}

// ================= launch =================
extern "C" void kernel_launch(void* const* d_in, const int* in_sizes, int n_in,
                              void* d_out, int out_size, void* d_ws, size_t ws_size,
                              hipStream_t stream) {
    const float* x = (const float*)d_in[0];
    const int* ei = (const int*)d_in[1];
    const float* ew = (const float*)d_in[2];
    const int* batch = (const int*)d_in[3];
    const float* W1 = (const float*)d_in[4];
    const float* b1 = (const float*)d_in[5];
    const float* W2 = (const float*)d_in[6];
    const float* b2 = (const float*)d_in[7];
    const float* W3 = (const float*)d_in[8];
    const float* b3 = (const float*)d_in[9];
    const float* linW = (const float*)d_in[10];
    const float* linb = (const float*)d_in[11];

    const int E = in_sizes[1] / 2;   // 1,600,000
    const int N = in_sizes[0] / 128; // 100,000
    const int* src = ei;
    const int* dst = ei + E;

    float* ws = (float*)d_ws;
    float* csr_w   = ws;                               // 1,600,256
    int*   csr_src = (int*)(ws + 1600256);             // 1,600,256
    int*   cursor  = csr_src + 1600256;                // 100,352
    float* dinv    = (float*)(cursor + 100352);        // 100,352
    int*   bsum    = (int*)(dinv + 100352);            // 256
    int*   boff    = bsum + 256;                       // 256
    float* U       = (float*)(boff + 256);             // 19,200,256 (N x 192)
    float* P12     = U + 19200256;                     // 12,800,256 (N x 128)
    float* H1      = P12 + 12800256;                   // 6,400,256  (N x 64)
    float* sums    = H1 + 6400256;                     // 8,192
    int*   starts  = (int*)(sums + 8192);              // 96

    float* A2 = U;                  // layer-2 temporaries alias U (free by then)
    float* B2 = U + 6400256;
    float* H2 = U + 12800512;
    float* A3 = P12;                // layer-3 temporaries alias P12
    float* B3 = P12 + 6400256;

    const int TB = 256;
    auto blocks = [](long long t, int b) { return (int)((t + b - 1) / b); };
    const int PG64  = blocks((long long)N * 16, TB);
    const int PG128 = blocks((long long)N * 32, TB);
    const int NB = (N + 1023) / 1024;  // 98 scan blocks

    // ---- degree + histogram + norm prep + CSR build ----
    hipMemsetAsync(dinv, 0, N * sizeof(float), stream);
    hipMemsetAsync(cursor, 0, N * sizeof(int), stream);
    k_degh<<<blocks(E, TB), TB, 0, stream>>>(src, dst, ew, dinv, cursor, E);
    k_dinv<<<blocks(N, TB), TB, 0, stream>>>(dinv, N);
    k_scan_a<<<NB, 1024, 0, stream>>>(cursor, bsum, N);
    k_scan_b<<<1, 128, 0, stream>>>(bsum, boff, NB);
    k_scan_c<<<NB, 1024, 0, stream>>>(cursor, boff, N);
    k_fill<<<blocks(E, TB), TB, 0, stream>>>(src, dst, ew, dinv, cursor, csr_src, csr_w, E);

    // ---- layer 1: U = x@[W0|W1|W2];
    //      [P1|P2] = prop([U1|U2]);  H1 = relu(U0 + P1 + 2*prop(P2) - U2 + b1)
    {
        dim3 g((N + 63) / 64, 3);
        k_gemmU<<<g, TB, 0, stream>>>(x, W1, U, N);
    }
    k_prop_csr<128, 0><<<PG128, TB, 0, stream>>>(cursor, csr_src, csr_w, U + 64, 192,
                                                 P12, 128, nullptr, nullptr, nullptr,
                                                 nullptr, nullptr, N);
    k_prop_csr<64, 2><<<PG64, TB, 0, stream>>>(cursor, csr_src, csr_w, P12 + 64, 128,
                                               H1, 64, nullptr, U, U + 128, P12, b1, N);

    // ---- layer 2 ----
    k_prop_csr<64, 0><<<PG64, TB, 0, stream>>>(cursor, csr_src, csr_w, H1, 64,
                                               A2, 64, nullptr, nullptr, nullptr,
                                               nullptr, nullptr, N);
    k_prop_csr<64, 1><<<PG64, TB, 0, stream>>>(cursor, csr_src, csr_w, A2, 64,
                                               B2, 64, H1, nullptr, nullptr,
                                               nullptr, nullptr, N);
    {
        dim3 g((N + 63) / 64, 1);
        k_gemm3<false><<<g, TB, 0, stream>>>(H1, A2, B2, W2, b2, H2, N, 64, 64, nullptr, nullptr);
    }

    // ---- layer 3: props + GEMM fused with mean-pool sums ----
    k_prop_csr<64, 0><<<PG64, TB, 0, stream>>>(cursor, csr_src, csr_w, H2, 64,
                                               A3, 64, nullptr, nullptr, nullptr,
                                               nullptr, nullptr, N);
    k_prop_csr<64, 1><<<PG64, TB, 0, stream>>>(cursor, csr_src, csr_w, A3, 64,
                                               B3, 64, H2, nullptr, nullptr,
                                               nullptr, nullptr, N);
    hipMemsetAsync(sums, 0, NG * 128 * sizeof(float), stream);
    {
        dim3 g((N + 63) / 64, 2);
        k_gemm3<true><<<g, TB, 0, stream>>>(H2, A3, B3, W3, b3, nullptr, N, 64, 128, batch, sums);
    }

    // ---- head ----
    k_starts<<<1, 128, 0, stream>>>(batch, starts, N);
    k_head<<<1, 640, 0, stream>>>(sums, starts, linW, linb, (float*)d_out);
}

// Round 4
// 926.856 us; speedup vs baseline: 13.0891x; 1.0987x over previous
//
#include <hip/hip_runtime.h>

#define NN 100000
#define NG 64

// ======================= shared GEMM body: 64x64 tile, U = x @ W[by] ========
// out stride 192, column base by*64. As padded to 68 for aligned b128 reads.
__device__ __forceinline__ void gemmU_body(const float* __restrict__ x,
                                           const float* __restrict__ W,
                                           float* __restrict__ U, int N,
                                           int bx, int by) {
    __shared__ float As[16][68];
    __shared__ float Bs[16][64];
    const float* Wk = W + by * (128 * 64);
    int row0 = bx * 64;
    int tid = threadIdx.x;
    int tr = tid >> 4, tc = tid & 15;
    float acc[4][4] = {};
    for (int k0 = 0; k0 < 128; k0 += 16) {
        {
            int r = row0 + (tid >> 2);
            int cc = (tid & 3) * 4;
            float4 v = make_float4(0.f, 0.f, 0.f, 0.f);
            if (r < N) v = *reinterpret_cast<const float4*>(x + (size_t)r * 128 + k0 + cc);
            As[cc + 0][tid >> 2] = v.x;
            As[cc + 1][tid >> 2] = v.y;
            As[cc + 2][tid >> 2] = v.z;
            As[cc + 3][tid >> 2] = v.w;
        }
        {
            int rr = tid >> 4;
            int cc = (tid & 15) * 4;
            *reinterpret_cast<float4*>(&Bs[rr][cc]) =
                *reinterpret_cast<const float4*>(Wk + (k0 + rr) * 64 + cc);
        }
        __syncthreads();
#pragma unroll
        for (int kk = 0; kk < 16; ++kk) {
            float4 a = *reinterpret_cast<const float4*>(&As[kk][tr * 4]);
            float4 b = *reinterpret_cast<const float4*>(&Bs[kk][tc * 4]);
            acc[0][0] += a.x * b.x; acc[0][1] += a.x * b.y; acc[0][2] += a.x * b.z; acc[0][3] += a.x * b.w;
            acc[1][0] += a.y * b.x; acc[1][1] += a.y * b.y; acc[1][2] += a.y * b.z; acc[1][3] += a.y * b.w;
            acc[2][0] += a.z * b.x; acc[2][1] += a.z * b.y; acc[2][2] += a.z * b.z; acc[2][3] += a.z * b.w;
            acc[3][0] += a.w * b.x; acc[3][1] += a.w * b.y; acc[3][2] += a.w * b.z; acc[3][3] += a.w * b.w;
        }
        __syncthreads();
    }
    int cbase = by * 64;
#pragma unroll
    for (int i = 0; i < 4; ++i) {
        int r = row0 + tr * 4 + i;
        if (r >= N) continue;
#pragma unroll
        for (int j = 0; j < 4; ++j)
            U[(size_t)r * 192 + cbase + tc * 4 + j] = acc[i][j];
    }
}

// ============ pre1: gemmU(y=0,1) fused with degree+histogram ================
__global__ __launch_bounds__(256) void k_pre1(const float* __restrict__ x,
                                              const float* __restrict__ W1,
                                              float* __restrict__ U, int N,
                                              const int* __restrict__ src,
                                              const int* __restrict__ dst,
                                              const float* __restrict__ ew,
                                              float* __restrict__ deg,
                                              int* __restrict__ cnt, int E,
                                              int gx) {
    int b = blockIdx.x;
    if (b < 2 * gx) {
        gemmU_body(x, W1, U, N, b % gx, b / gx);
    } else {
        int e = (b - 2 * gx) * 256 + threadIdx.x;
        if (e < E) {
            atomicAdd(&deg[src[e]], ew[e]);
            atomicAdd(&cnt[dst[e]], 1);
        }
    }
}

// ============ pre2: gemmU(y=2) fused with CSR fill (packed int2) ============
__global__ __launch_bounds__(256) void k_pre2(const float* __restrict__ x,
                                              const float* __restrict__ W1,
                                              float* __restrict__ U, int N,
                                              const int* __restrict__ src,
                                              const int* __restrict__ dst,
                                              const float* __restrict__ ew,
                                              const float* __restrict__ dinv,
                                              int* __restrict__ cursor,
                                              int2* __restrict__ csr, int E,
                                              int gx) {
    int b = blockIdx.x;
    if (b < gx) {
        gemmU_body(x, W1, U, N, b, 2);
    } else {
        int e = (b - gx) * 256 + threadIdx.x;
        if (e < E) {
            int s = src[e], d = dst[e];
            int pos = atomicAdd(&cursor[d], 1);
            float w = -dinv[s] * ew[e] * dinv[d];
            csr[pos] = make_int2(s, __float_as_int(w));
        }
    }
}

// ================= scan pass A (+ fused dinv) =================
__global__ __launch_bounds__(1024) void k_scan_a(int* __restrict__ cnt,
                                                 int* __restrict__ bsum,
                                                 float* __restrict__ deg, int N) {
    __shared__ int sh[1024];
    int t = threadIdx.x;
    int idx = blockIdx.x * 1024 + t;
    int v = (idx < N) ? cnt[idx] : 0;
    if (idx < N) {
        float d = deg[idx];
        deg[idx] = (d > 0.f) ? rsqrtf(fmaxf(d, 1e-30f)) : 0.f;
    }
    sh[t] = v;
    __syncthreads();
#pragma unroll
    for (int off = 1; off < 1024; off <<= 1) {
        int tmp = (t >= off) ? sh[t - off] : 0;
        __syncthreads();
        sh[t] += tmp;
        __syncthreads();
    }
    if (idx < N) cnt[idx] = sh[t] - v;  // exclusive
    if (t == 1023) bsum[blockIdx.x] = sh[1023];
}

__global__ __launch_bounds__(128) void k_scan_b(const int* __restrict__ bsum,
                                                int* __restrict__ boff, int nb) {
    __shared__ int sh[128];
    int t = threadIdx.x;
    int v = (t < nb) ? bsum[t] : 0;
    sh[t] = v;
    __syncthreads();
#pragma unroll
    for (int off = 1; off < 128; off <<= 1) {
        int tmp = (t >= off) ? sh[t - off] : 0;
        __syncthreads();
        sh[t] += tmp;
        __syncthreads();
    }
    if (t < nb) boff[t] = sh[t] - v;
}

__global__ __launch_bounds__(1024) void k_scan_c(int* __restrict__ cnt,
                                                 const int* __restrict__ boff, int N) {
    int idx = blockIdx.x * 1024 + threadIdx.x;
    if (idx < N) cnt[idx] += boff[blockIdx.x];
}

// ================= propagation (CSR gather, packed int2) =================
// MODE 0: out = acc
// MODE 1: out = 2*acc - t0                  (t0 stride 64)
// MODE 2: out = relu(u0 + p1 + 2*acc - u2 + bias)
//         (u0,u2 stride 192; p1 stride 128; out stride 64; F must be 64)
template <int F, int MODE>
__global__ __launch_bounds__(256) void k_prop_csr(const int* __restrict__ rowend,
                                                  const int2* __restrict__ csr,
                                                  const float* __restrict__ in,
                                                  int istride,
                                                  float* __restrict__ out,
                                                  int ostride,
                                                  const float* __restrict__ t0,
                                                  const float* __restrict__ u0,
                                                  const float* __restrict__ u2,
                                                  const float* __restrict__ p1,
                                                  const float* __restrict__ bias,
                                                  int N) {
    const int CPE = F / 4;
    int tid = blockIdx.x * 256 + threadIdx.x;
    int node = tid / CPE;
    int lane = tid % CPE;
    if (node >= N) return;
    int start = (node == 0) ? 0 : rowend[node - 1];
    int end = rowend[node];
    float4 acc = make_float4(0.f, 0.f, 0.f, 0.f);
    int c4 = lane * 4;
    int j = start;
    for (; j + 4 <= end; j += 4) {
        int2 e0 = csr[j + 0], e1 = csr[j + 1], e2 = csr[j + 2], e3 = csr[j + 3];
        float w0 = __int_as_float(e0.y), w1 = __int_as_float(e1.y);
        float w2 = __int_as_float(e2.y), w3 = __int_as_float(e3.y);
        float4 v0 = *reinterpret_cast<const float4*>(in + (size_t)e0.x * istride + c4);
        float4 v1 = *reinterpret_cast<const float4*>(in + (size_t)e1.x * istride + c4);
        float4 v2 = *reinterpret_cast<const float4*>(in + (size_t)e2.x * istride + c4);
        float4 v3 = *reinterpret_cast<const float4*>(in + (size_t)e3.x * istride + c4);
        acc.x += w0 * v0.x + w1 * v1.x + w2 * v2.x + w3 * v3.x;
        acc.y += w0 * v0.y + w1 * v1.y + w2 * v2.y + w3 * v3.y;
        acc.z += w0 * v0.z + w1 * v1.z + w2 * v2.z + w3 * v3.z;
        acc.w += w0 * v0.w + w1 * v1.w + w2 * v2.w + w3 * v3.w;
    }
    for (; j < end; ++j) {
        int2 e0 = csr[j];
        float w0 = __int_as_float(e0.y);
        float4 v0 = *reinterpret_cast<const float4*>(in + (size_t)e0.x * istride + c4);
        acc.x += w0 * v0.x;
        acc.y += w0 * v0.y;
        acc.z += w0 * v0.z;
        acc.w += w0 * v0.w;
    }
    float4 r;
    if (MODE == 0) {
        r = acc;
    } else if (MODE == 1) {
        float4 t = *reinterpret_cast<const float4*>(t0 + (size_t)node * 64 + c4);
        r.x = 2.f * acc.x - t.x;
        r.y = 2.f * acc.y - t.y;
        r.z = 2.f * acc.z - t.z;
        r.w = 2.f * acc.w - t.w;
    } else {
        float4 a = *reinterpret_cast<const float4*>(u0 + (size_t)node * 192 + c4);
        float4 b = *reinterpret_cast<const float4*>(u2 + (size_t)node * 192 + c4);
        float4 p = *reinterpret_cast<const float4*>(p1 + (size_t)node * 128 + c4);
        float4 bb = *reinterpret_cast<const float4*>(bias + c4);
        r.x = fmaxf(a.x + p.x + 2.f * acc.x - b.x + bb.x, 0.f);
        r.y = fmaxf(a.y + p.y + 2.f * acc.y - b.y + bb.y, 0.f);
        r.z = fmaxf(a.z + p.z + 2.f * acc.z - b.z + bb.z, 0.f);
        r.w = fmaxf(a.w + p.w + 2.f * acc.w - b.w + bb.w, 0.f);
    }
    *reinterpret_cast<float4*>(out + (size_t)node * ostride + c4) = r;
}

// ====== 3-term GEMM: out = relu(T0@W0 + T1@W1 + T2@W2 + b); optional pool ===
template <bool POOL>
__global__ __launch_bounds__(256) void k_gemm3(const float* __restrict__ T0,
                                               const float* __restrict__ T1,
                                               const float* __restrict__ T2,
                                               const float* __restrict__ W,
                                               const float* __restrict__ bias,
                                               float* __restrict__ out,
                                               int N, int Fin, int Fout,
                                               const int* __restrict__ batch,
                                               float* __restrict__ sums) {
    __shared__ float As[16][68];
    __shared__ float Bs[16][64];
    int row0 = blockIdx.x * 64;
    int col0 = blockIdx.y * 64;
    int tid = threadIdx.x;
    int tr = tid >> 4, tc = tid & 15;
    float acc[4][4] = {};
    const float* Ts[3] = {T0, T1, T2};
    for (int k = 0; k < 3; ++k) {
        const float* T = Ts[k];
        const float* Wk = W + k * Fin * Fout;
        for (int k0 = 0; k0 < Fin; k0 += 16) {
            {
                int r = row0 + (tid >> 2);
                int cc = (tid & 3) * 4;
                float4 v = make_float4(0.f, 0.f, 0.f, 0.f);
                if (r < N)
                    v = *reinterpret_cast<const float4*>(T + (size_t)r * Fin + k0 + cc);
                As[cc + 0][tid >> 2] = v.x;
                As[cc + 1][tid >> 2] = v.y;
                As[cc + 2][tid >> 2] = v.z;
                As[cc + 3][tid >> 2] = v.w;
            }
            {
                int rr = tid >> 4;
                int cc = (tid & 15) * 4;
                *reinterpret_cast<float4*>(&Bs[rr][cc]) =
                    *reinterpret_cast<const float4*>(Wk + (size_t)(k0 + rr) * Fout + col0 + cc);
            }
            __syncthreads();
#pragma unroll
            for (int kk = 0; kk < 16; ++kk) {
                float4 a = *reinterpret_cast<const float4*>(&As[kk][tr * 4]);
                float4 b = *reinterpret_cast<const float4*>(&Bs[kk][tc * 4]);
                acc[0][0] += a.x * b.x; acc[0][1] += a.x * b.y; acc[0][2] += a.x * b.z; acc[0][3] += a.x * b.w;
                acc[1][0] += a.y * b.x; acc[1][1] += a.y * b.y; acc[1][2] += a.y * b.z; acc[1][3] += a.y * b.w;
                acc[2][0] += a.z * b.x; acc[2][1] += a.z * b.y; acc[2][2] += a.z * b.z; acc[2][3] += a.z * b.w;
                acc[3][0] += a.w * b.x; acc[3][1] += a.w * b.y; acc[3][2] += a.w * b.z; acc[3][3] += a.w * b.w;
            }
            __syncthreads();
        }
    }
    if (!POOL) {
#pragma unroll
        for (int i = 0; i < 4; ++i) {
            int r = row0 + tr * 4 + i;
            if (r >= N) continue;
#pragma unroll
            for (int j = 0; j < 4; ++j) {
                int cgl = col0 + tc * 4 + j;
                out[(size_t)r * Fout + cgl] = fmaxf(acc[i][j] + bias[cgl], 0.f);
            }
        }
    } else {
        __shared__ float ps[64];
        int b0 = batch[row0];
        int b1v = batch[min(row0 + 63, N - 1)];
        if (b0 == b1v) {
            if (tid < 64) ps[tid] = 0.f;
            __syncthreads();
#pragma unroll
            for (int j = 0; j < 4; ++j) {
                float cs = 0.f;
#pragma unroll
                for (int i = 0; i < 4; ++i) {
                    int r = row0 + tr * 4 + i;
                    if (r < N) cs += fmaxf(acc[i][j] + bias[col0 + tc * 4 + j], 0.f);
                }
                atomicAdd(&ps[tc * 4 + j], cs);
            }
            __syncthreads();
            if (tid < 64) atomicAdd(&sums[b0 * 128 + col0 + tid], ps[tid]);
        } else {
#pragma unroll
            for (int i = 0; i < 4; ++i) {
                int r = row0 + tr * 4 + i;
                if (r >= N) continue;
#pragma unroll
                for (int j = 0; j < 4; ++j) {
                    int cgl = col0 + tc * 4 + j;
                    float v = fmaxf(acc[i][j] + bias[cgl], 0.f);
                    atomicAdd(&sums[batch[r] * 128 + cgl], v);
                }
            }
        }
    }
}

// ================= head (graph starts computed in-kernel) =================
__global__ __launch_bounds__(640) void k_head(const float* __restrict__ sums,
                                              const int* __restrict__ batch, int N,
                                              const float* __restrict__ linW,
                                              const float* __restrict__ linb,
                                              float* __restrict__ out) {
    __shared__ int st[65];
    int t = threadIdx.x;
    if (t <= 64) {
        if (t == 64) {
            st[64] = N;
        } else {
            int lo = 0, hi = N;
            while (lo < hi) {
                int mid = (lo + hi) >> 1;
                if (batch[mid] < t) lo = mid + 1; else hi = mid;
            }
            st[t] = lo;
        }
    }
    __syncthreads();
    if (t >= NG * 10) return;
    int g = t / 10, o = t % 10;
    float cnt = (float)(st[g + 1] - st[g]);
    float inv = 1.f / fmaxf(cnt, 1.f);
    float acc = 0.f;
#pragma unroll 8
    for (int k = 0; k < 128; ++k) acc += sums[g * 128 + k] * linW[k * 10 + o];
    out[t] = acc * inv + linb[o];
}

// ================= launch =================
extern "C" void kernel_launch(void* const* d_in, const int* in_sizes, int n_in,
                              void* d_out, int out_size, void* d_ws, size_t ws_size,
                              hipStream_t stream) {
    const float* x = (const float*)d_in[0];
    const int* ei = (const int*)d_in[1];
    const float* ew = (const float*)d_in[2];
    const int* batch = (const int*)d_in[3];
    const float* W1 = (const float*)d_in[4];
    const float* b1 = (const float*)d_in[5];
    const float* W2 = (const float*)d_in[6];
    const float* b2 = (const float*)d_in[7];
    const float* W3 = (const float*)d_in[8];
    const float* b3 = (const float*)d_in[9];
    const float* linW = (const float*)d_in[10];
    const float* linb = (const float*)d_in[11];

    const int E = in_sizes[1] / 2;   // 1,600,000
    const int N = in_sizes[0] / 128; // 100,000
    const int* src = ei;
    const int* dst = ei + E;

    float* ws = (float*)d_ws;
    int2*  csr     = (int2*)ws;                        // 1,600,256 entries (8B)
    int*   cursor  = (int*)(ws + 3200512);             // 100,352
    float* dinv    = ws + 3200512 + 100352;            // 100,352 (deg then dinv)
    int*   bsum    = (int*)(dinv + 100352);            // 256
    int*   boff    = bsum + 256;                       // 256
    float* U       = (float*)(boff + 256);             // 19,200,256 (N x 192)
    float* P12     = U + 19200256;                     // 12,800,256 (N x 128)
    float* H1      = P12 + 12800256;                   // 6,400,256  (N x 64)
    float* sums    = H1 + 6400256;                     // 8,192

    float* A2 = U;                  // layer-2 temporaries alias U (free by then)
    float* B2 = U + 6400256;
    float* H2 = U + 12800512;
    float* A3 = P12;                // layer-3 temporaries alias P12
    float* B3 = P12 + 6400256;

    const int TB = 256;
    auto blocks = [](long long t, int b) { return (int)((t + b - 1) / b); };
    const int PG64  = blocks((long long)N * 16, TB);
    const int PG128 = blocks((long long)N * 32, TB);
    const int NB = (N + 1023) / 1024;       // scan blocks
    const int GX = (N + 63) / 64;           // gemmU x-blocks
    const int EB = blocks(E, TB);           // edge blocks

    // ---- pre1: gemmU(y0,y1) + degree/histogram ----
    hipMemsetAsync(cursor, 0, 2 * 100352 * sizeof(float), stream);  // cursor + deg
    k_pre1<<<2 * GX + EB, TB, 0, stream>>>(x, W1, U, N, src, dst, ew, dinv, cursor, E, GX);
    // ---- dinv + scan ----
    k_scan_a<<<NB, 1024, 0, stream>>>(cursor, bsum, dinv, N);
    k_scan_b<<<1, 128, 0, stream>>>(bsum, boff, NB);
    k_scan_c<<<NB, 1024, 0, stream>>>(cursor, boff, N);
    // ---- pre2: gemmU(y2) + CSR fill ----
    k_pre2<<<GX + EB, TB, 0, stream>>>(x, W1, U, N, src, dst, ew, dinv, cursor, csr, E, GX);

    // ---- layer 1: [P1|P2] = prop([U1|U2]); H1 = relu(U0 + P1 + 2*prop(P2) - U2 + b1)
    k_prop_csr<128, 0><<<PG128, TB, 0, stream>>>(cursor, csr, U + 64, 192,
                                                 P12, 128, nullptr, nullptr, nullptr,
                                                 nullptr, nullptr, N);
    k_prop_csr<64, 2><<<PG64, TB, 0, stream>>>(cursor, csr, P12 + 64, 128,
                                               H1, 64, nullptr, U, U + 128, P12, b1, N);

    // ---- layer 2 ----
    k_prop_csr<64, 0><<<PG64, TB, 0, stream>>>(cursor, csr, H1, 64, A2, 64,
                                               nullptr, nullptr, nullptr, nullptr, nullptr, N);
    k_prop_csr<64, 1><<<PG64, TB, 0, stream>>>(cursor, csr, A2, 64, B2, 64,
                                               H1, nullptr, nullptr, nullptr, nullptr, N);
    {
        dim3 g(GX, 1);
        k_gemm3<false><<<g, TB, 0, stream>>>(H1, A2, B2, W2, b2, H2, N, 64, 64, nullptr, nullptr);
    }

    // ---- layer 3: props + GEMM fused with mean-pool sums ----
    k_prop_csr<64, 0><<<PG64, TB, 0, stream>>>(cursor, csr, H2, 64, A3, 64,
                                               nullptr, nullptr, nullptr, nullptr, nullptr, N);
    k_prop_csr<64, 1><<<PG64, TB, 0, stream>>>(cursor, csr, A3, 64, B3, 64,
                                               H2, nullptr, nullptr, nullptr, nullptr, N);
    hipMemsetAsync(sums, 0, NG * 128 * sizeof(float), stream);
    {
        dim3 g(GX, 2);
        k_gemm3<true><<<g, TB, 0, stream>>>(H2, A3, B3, W3, b3, nullptr, N, 64, 128, batch, sums);
    }

    // ---- head ----
    k_head<<<1, 640, 0, stream>>>(sums, batch, N, linW, linb, (float*)d_out);
}